// Round 6
// baseline (180.061 us; speedup 1.0000x reference)
//
#include <hip/hip_runtime.h>
#include <hip/hip_bf16.h>
#include <stdint.h>

// Spiking ensemble update. S=16384. W=[S][S] f32 (1 GiB). lateral = spikes @ W:
// only spiking rows (~50%) read -> ~537 MB floor ~ 84 us @ 6.4 TB/s.
// Outputs: flat f32 concat [spikes, activation, threshold, freq].
// R2 branchy: 2.1 TB/s (latency). R3 compacted 4KB slices: 3.7. R4 16KB+NT: 5.4.
// R5 balance/f32 partials: NEUTRAL (grids self-balance via backfill).
// R6: full-64KB-row blocks (TPB=1024), cached loads (drop NT), 16-deep MLP.

constexpr int S = 16384;
constexpr int TPB = 256;       // prep / update
constexpr int TPB_L = 1024;    // lateral: block covers full row width
constexpr int N_CHUNKS = 512;  // npc <= 32
constexpr int MAX_NPC = 32;

typedef float  f32x4 __attribute__((ext_vector_type(4)));

// dtype code: 0=int32, 1=uint8/bool, 2=f32, 3=bf16
__device__ __forceinline__ bool spike_flag(const void* sp, int c, int r) {
  if (c == 0) return ((const int*)sp)[r] != 0;
  if (c == 1) return ((const unsigned char*)sp)[r] != 0;
  if (c == 2) return ((const float*)sp)[r] != 0.0f;
  return ((const unsigned short*)sp)[r] != 0;
}

// ---- prep: classify dtype + globally compact spiking rows (1 block) ----
__global__ __launch_bounds__(TPB) void prep(
    const void* __restrict__ sp, int* __restrict__ idx, int* __restrict__ total) {
  __shared__ int s3F_any, s3F_odd, sNZ_off;
  __shared__ int code_s;
  __shared__ int wcnt[S / 64];  // 256 per-(iter,wave) counts -> exclusive prefix
  const int tid = threadIdx.x, lane = tid & 63, wv = tid >> 6;

  if (tid == 0) { s3F_any = 0; s3F_odd = 0; sNZ_off = 0; }
  __syncthreads();
  int l3a = 0, l3o = 0, lnz = 0;
  const uint32_t* spw = (const uint32_t*)sp;
  for (int w = tid; w < S / 4; w += TPB) {
    uint32_t v = spw[w];
#pragma unroll
    for (int b = 0; b < 4; ++b) {
      unsigned char byte = (v >> (8 * b)) & 0xFF;
      int i = w * 4 + b;
      if (byte == 0x3F) { l3a = 1; if ((i & 3) == 1) l3o = 1; }
      if (byte != 0 && (i & 3) != 0) lnz = 1;
    }
  }
  if (l3a) atomicOr(&s3F_any, 1);
  if (l3o) atomicOr(&s3F_odd, 1);
  if (lnz) atomicOr(&sNZ_off, 1);
  __syncthreads();
  if (tid == 0)
    code_s = s3F_any ? (s3F_odd ? 3 : 2) : (sNZ_off ? 1 : 0);
  __syncthreads();
  const int c = code_s;

  // pass 1: per-(iter,wave) spike counts
  for (int it = 0; it < S / TPB; ++it) {
    bool f = spike_flag(sp, c, it * TPB + tid);
    unsigned long long m = __ballot(f);
    if (lane == 0) wcnt[it * 4 + wv] = __popcll(m);
  }
  __syncthreads();
  // wave-parallel exclusive scan of the 256 counts (wave 0)
  if (tid < 64) {
    int e0 = wcnt[4 * tid], e1 = wcnt[4 * tid + 1];
    int e2 = wcnt[4 * tid + 2], e3 = wcnt[4 * tid + 3];
    int p1 = e0, p2 = e0 + e1, p3 = e0 + e1 + e2;
    int sum = p3 + e3;
    int incl = sum;
#pragma unroll
    for (int d = 1; d < 64; d <<= 1) {
      int t = __shfl_up(incl, d, 64);
      if (tid >= d) incl += t;
    }
    int excl = incl - sum;
    wcnt[4 * tid] = excl;
    wcnt[4 * tid + 1] = excl + p1;
    wcnt[4 * tid + 2] = excl + p2;
    wcnt[4 * tid + 3] = excl + p3;
    if (tid == 63) *total = incl;
  }
  __syncthreads();
  // pass 2: ordered scatter
  for (int it = 0; it < S / TPB; ++it) {
    int r = it * TPB + tid;
    bool f = spike_flag(sp, c, r);
    unsigned long long m = __ballot(f);
    int within = __popcll(m & ((1ULL << lane) - 1ULL));
    if (f) idx[wcnt[it * 4 + wv] + within] = r;
  }
}

// ---- hot kernel: one block reads FULL 64KB rows; 16 loads in flight ----
__global__ __launch_bounds__(TPB_L) void lateral_fullrow(
    const float* __restrict__ W, const int* __restrict__ idx,
    const int* __restrict__ total, float* __restrict__ partial) {
  const int b = blockIdx.x;
  const int tot = *total;
  const int npc = (tot + N_CHUNKS - 1) / N_CHUNKS;   // <= 32
  const int start = b * npc;
  const int n = max(0, min(npc, tot - start));
  __shared__ int ids[MAX_NPC];
  if (threadIdx.x < MAX_NPC)
    ids[threadIdx.x] = (threadIdx.x < n) ? idx[start + threadIdx.x] : 0;
  __syncthreads();

  const float* Wc = W + threadIdx.x * 4;   // + s*4096 slices cover the row
  f32x4 a0 = 0.0f, a1 = 0.0f, a2 = 0.0f, a3 = 0.0f;
  int i = 0;
  for (; i + 4 <= n; i += 4) {
    f32x4 w0[4], w1[4], w2[4], w3[4];
#pragma unroll
    for (int u = 0; u < 4; ++u) {
      const float* p = Wc + (size_t)ids[i + u] * S;
      w0[u] = *(const f32x4*)(p);
      w1[u] = *(const f32x4*)(p + 4096);
      w2[u] = *(const f32x4*)(p + 8192);
      w3[u] = *(const f32x4*)(p + 12288);
    }
    a0 += (w0[0] + w0[1]) + (w0[2] + w0[3]);
    a1 += (w1[0] + w1[1]) + (w1[2] + w1[3]);
    a2 += (w2[0] + w2[1]) + (w2[2] + w2[3]);
    a3 += (w3[0] + w3[1]) + (w3[2] + w3[3]);
  }
  for (; i < n; ++i) {
    const float* p = Wc + (size_t)ids[i] * S;
    a0 += *(const f32x4*)(p);
    a1 += *(const f32x4*)(p + 4096);
    a2 += *(const f32x4*)(p + 8192);
    a3 += *(const f32x4*)(p + 12288);
  }
  float* dst = partial + (size_t)b * S + threadIdx.x * 4;
  *(f32x4*)(dst)         = a0;
  *(f32x4*)(dst + 4096)  = a1;
  *(f32x4*)(dst + 8192)  = a2;
  *(f32x4*)(dst + 12288) = a3;
}

// ---- reduce 512 f32 partials (f64 chains) + fused epilogue ----
__device__ __forceinline__ void ensemble_epilogue(
    int j, float lateral,
    const float* __restrict__ x, const float* __restrict__ act,
    const float* __restrict__ thr, const float* __restrict__ freq,
    float* __restrict__ out) {
  float na = 0.9f * act[j] + x[j] + lateral;
  float t = thr[j];
  bool sp = na > t;
  float nf = 0.95f * freq[j] + 0.05f * (sp ? 1.0f : 0.0f);
  float nt = (nf > 0.2f) ? (t + 0.05f) : ((nf < 0.2f) ? (t / 1.05f) : t);
  if (sp) na = 0.0f;
  out[j]         = sp ? 1.0f : 0.0f;
  out[S + j]     = na;
  out[2 * S + j] = nt;
  out[3 * S + j] = nf;
}

__global__ __launch_bounds__(TPB) void ensemble_update(
    const float* __restrict__ partial,
    const float* __restrict__ x, const float* __restrict__ act,
    const float* __restrict__ thr, const float* __restrict__ freq,
    float* __restrict__ out) {
  const int j = blockIdx.x * TPB + threadIdx.x;
  double l0 = 0.0, l1 = 0.0, l2 = 0.0, l3 = 0.0;
#pragma unroll 4
  for (int c = 0; c < N_CHUNKS; c += 4) {
    l0 += (double)partial[(size_t)c * S + j];
    l1 += (double)partial[(size_t)(c + 1) * S + j];
    l2 += (double)partial[(size_t)(c + 2) * S + j];
    l3 += (double)partial[(size_t)(c + 3) * S + j];
  }
  ensemble_epilogue(j, (float)((l0 + l1) + (l2 + l3)), x, act, thr, freq, out);
}

// ---- minimal fallback (ws too small; assumes int32 spikes) ----
__global__ __launch_bounds__(TPB) void fused_full_int(
    const float* __restrict__ W, const int* __restrict__ spikes,
    const float* __restrict__ x, const float* __restrict__ act,
    const float* __restrict__ thr, const float* __restrict__ freq,
    float* __restrict__ out) {
  const int j = blockIdx.x * TPB + threadIdx.x;
  double lat = 0.0;
  for (int i = 0; i < S; ++i)
    if (spikes[i] != 0) lat += (double)W[(size_t)i * S + j];
  ensemble_epilogue(j, (float)lat, x, act, thr, freq, out);
}

extern "C" void kernel_launch(void* const* d_in, const int* in_sizes, int n_in,
                              void* d_out, int out_size, void* d_ws, size_t ws_size,
                              hipStream_t stream) {
  const float* x    = (const float*)d_in[0];
  const float* act  = (const float*)d_in[1];
  const float* thr  = (const float*)d_in[2];
  const float* freq = (const float*)d_in[3];
  const float* W    = (const float*)d_in[4];
  const void*  sp   = d_in[5];
  float* out = (float*)d_out;

  // ws: total@0 | idx i32 @4096 (64K) | partial f32 @1M (512*16384*4 = 32 MB)
  const size_t PART_OFF = 1 << 20;
  const size_t need = PART_OFF + (size_t)N_CHUNKS * S * sizeof(float);

  if (ws_size >= need) {
    int* total     = (int*)d_ws;
    int* idx       = (int*)((char*)d_ws + 4096);
    float* partial = (float*)((char*)d_ws + PART_OFF);

    prep<<<1, TPB, 0, stream>>>(sp, idx, total);
    lateral_fullrow<<<N_CHUNKS, TPB_L, 0, stream>>>(W, idx, total, partial);
    ensemble_update<<<S / TPB, TPB, 0, stream>>>(partial, x, act, thr, freq, out);
  } else {
    fused_full_int<<<S / TPB, TPB, 0, stream>>>(W, (const int*)sp, x, act, thr, freq, out);
  }
}

// Round 7
// 105.236 us; speedup vs baseline: 1.7110x; 1.7110x over previous
//
#include <hip/hip_runtime.h>
#include <hip/hip_bf16.h>
#include <stdint.h>

// Spiking ensemble update. S=16384. W=[S][S] f32 (1 GiB). lateral = spikes @ W:
// only spiking rows (~50%) read -> ~537 MB floor ~ 84-90 us at read ceiling.
// Outputs: flat f32 concat [spikes, activation, threshold, freq].
// History: R2 branchy 2.1 TB/s; R3 compact+4KB 3.7; R4 16KB+NT 5.4; R5 global
// equal-partition NEUTRAL (backfill self-balances); R6 TPB=1024 full-row
// REGRESSED (1 block/CU -> 2 strict rounds, no overlap). R7: revert to R5
// body, fuse prep into lateral (per-block self-compaction of its 64 rows).

constexpr int S = 16384;
constexpr int TPB = 256;
constexpr int RPC = 64;          // rows per chunk (fixed range, one ballot)
constexpr int N_CHUNKS = S / RPC;          // 256
constexpr int COL_BLOCKS = 4;              // 4096 cols = 16 KB per row visit
constexpr int COLW = S / COL_BLOCKS;

typedef float  f32x4 __attribute__((ext_vector_type(4)));
typedef double f64x4 __attribute__((ext_vector_type(4)));

// dtype code: 0=int32, 1=uint8/bool, 2=f32, 3=bf16
__device__ __forceinline__ bool spike_flag(const void* sp, int c, int r) {
  if (c == 0) return ((const int*)sp)[r] != 0;
  if (c == 1) return ((const unsigned char*)sp)[r] != 0;
  if (c == 2) return ((const float*)sp)[r] != 0.0f;
  return ((const unsigned short*)sp)[r] != 0;
}

// Classify spike storage dtype from first S bytes (L2-hot after first block).
__device__ __forceinline__ int classify_local(const uint32_t* spw, int tid,
                                              int* sh3) {
  int l3a = 0, l3o = 0, lnz = 0;
  for (int w = tid; w < S / 4; w += TPB) {
    uint32_t v = spw[w];
#pragma unroll
    for (int b = 0; b < 4; ++b) {
      unsigned char byte = (v >> (8 * b)) & 0xFF;
      int i = w * 4 + b;
      if (byte == 0x3F) { l3a = 1; if ((i & 3) == 1) l3o = 1; }
      if (byte != 0 && (i & 3) != 0) lnz = 1;
    }
  }
  if (l3a) atomicOr(&sh3[0], 1);
  if (l3o) atomicOr(&sh3[1], 1);
  if (lnz) atomicOr(&sh3[2], 1);
  __syncthreads();
  return sh3[0] ? (sh3[1] ? 3 : 2) : (sh3[2] ? 1 : 0);
}

// ---- hot kernel: self-prep (classify + ballot-compact own 64 rows), then
// stream 16 KB NT slices of each spiking row. grid (COL_BLOCKS, N_CHUNKS). ----
__global__ __launch_bounds__(TPB) void lateral_selfprep(
    const float* __restrict__ W, const void* __restrict__ sp,
    float* __restrict__ partial) {
  __shared__ int sh3[3];
  __shared__ int ids[RPC];
  __shared__ int n_s;
  const int tid = threadIdx.x;
  if (tid < 3) sh3[tid] = 0;
  __syncthreads();
  const int c = classify_local((const uint32_t*)sp, tid, sh3);

  const int b = blockIdx.y;            // row chunk
  const int q = blockIdx.x;            // column quarter
  // one wave compacts the chunk's 64 rows (ascending order preserved)
  if (tid < 64) {
    int r = b * RPC + tid;
    bool f = spike_flag(sp, c, r);
    unsigned long long m = __ballot(f);
    int within = __popcll(m & ((1ULL << tid) - 1ULL));
    if (f) ids[within] = r;
    if (tid == 0) n_s = __popcll(m);
  }
  __syncthreads();
  const int n = n_s;

  const float* Wc = W + q * COLW + tid * 4;
  f64x4 a0 = 0.0, a1 = 0.0, a2 = 0.0, a3 = 0.0;
  int i = 0;
  for (; i + 2 <= n; i += 2) {
    const float* pa = Wc + (size_t)ids[i] * S;
    const float* pb = Wc + (size_t)ids[i + 1] * S;
    f32x4 wa0 = __builtin_nontemporal_load((const f32x4*)(pa));
    f32x4 wa1 = __builtin_nontemporal_load((const f32x4*)(pa + 1024));
    f32x4 wa2 = __builtin_nontemporal_load((const f32x4*)(pa + 2048));
    f32x4 wa3 = __builtin_nontemporal_load((const f32x4*)(pa + 3072));
    f32x4 wb0 = __builtin_nontemporal_load((const f32x4*)(pb));
    f32x4 wb1 = __builtin_nontemporal_load((const f32x4*)(pb + 1024));
    f32x4 wb2 = __builtin_nontemporal_load((const f32x4*)(pb + 2048));
    f32x4 wb3 = __builtin_nontemporal_load((const f32x4*)(pb + 3072));
    a0 += __builtin_convertvector(wa0, f64x4) + __builtin_convertvector(wb0, f64x4);
    a1 += __builtin_convertvector(wa1, f64x4) + __builtin_convertvector(wb1, f64x4);
    a2 += __builtin_convertvector(wa2, f64x4) + __builtin_convertvector(wb2, f64x4);
    a3 += __builtin_convertvector(wa3, f64x4) + __builtin_convertvector(wb3, f64x4);
  }
  if (i < n) {
    const float* pa = Wc + (size_t)ids[i] * S;
    a0 += __builtin_convertvector(__builtin_nontemporal_load((const f32x4*)(pa)), f64x4);
    a1 += __builtin_convertvector(__builtin_nontemporal_load((const f32x4*)(pa + 1024)), f64x4);
    a2 += __builtin_convertvector(__builtin_nontemporal_load((const f32x4*)(pa + 2048)), f64x4);
    a3 += __builtin_convertvector(__builtin_nontemporal_load((const f32x4*)(pa + 3072)), f64x4);
  }
  float* dst = partial + (size_t)b * S + q * COLW + tid * 4;
  *(f32x4*)(dst)        = __builtin_convertvector(a0, f32x4);
  *(f32x4*)(dst + 1024) = __builtin_convertvector(a1, f32x4);
  *(f32x4*)(dst + 2048) = __builtin_convertvector(a2, f32x4);
  *(f32x4*)(dst + 3072) = __builtin_convertvector(a3, f32x4);
}

// ---- reduce 256 f32 partials (f64 chains) + fused epilogue ----
__device__ __forceinline__ void ensemble_epilogue(
    int j, float lateral,
    const float* __restrict__ x, const float* __restrict__ act,
    const float* __restrict__ thr, const float* __restrict__ freq,
    float* __restrict__ out) {
  float na = 0.9f * act[j] + x[j] + lateral;
  float t = thr[j];
  bool sp = na > t;
  float nf = 0.95f * freq[j] + 0.05f * (sp ? 1.0f : 0.0f);
  float nt = (nf > 0.2f) ? (t + 0.05f) : ((nf < 0.2f) ? (t / 1.05f) : t);
  if (sp) na = 0.0f;
  out[j]         = sp ? 1.0f : 0.0f;
  out[S + j]     = na;
  out[2 * S + j] = nt;
  out[3 * S + j] = nf;
}

__global__ __launch_bounds__(TPB) void ensemble_update(
    const float* __restrict__ partial,
    const float* __restrict__ x, const float* __restrict__ act,
    const float* __restrict__ thr, const float* __restrict__ freq,
    float* __restrict__ out) {
  const int j = blockIdx.x * TPB + threadIdx.x;
  double l0 = 0.0, l1 = 0.0, l2 = 0.0, l3 = 0.0;
#pragma unroll 8
  for (int c = 0; c < N_CHUNKS; c += 4) {
    l0 += (double)partial[(size_t)c * S + j];
    l1 += (double)partial[(size_t)(c + 1) * S + j];
    l2 += (double)partial[(size_t)(c + 2) * S + j];
    l3 += (double)partial[(size_t)(c + 3) * S + j];
  }
  ensemble_epilogue(j, (float)((l0 + l1) + (l2 + l3)), x, act, thr, freq, out);
}

// ---- minimal fallback (ws too small; assumes int32 spikes) ----
__global__ __launch_bounds__(TPB) void fused_full_int(
    const float* __restrict__ W, const int* __restrict__ spikes,
    const float* __restrict__ x, const float* __restrict__ act,
    const float* __restrict__ thr, const float* __restrict__ freq,
    float* __restrict__ out) {
  const int j = blockIdx.x * TPB + threadIdx.x;
  double lat = 0.0;
  for (int i = 0; i < S; ++i)
    if (spikes[i] != 0) lat += (double)W[(size_t)i * S + j];
  ensemble_epilogue(j, (float)lat, x, act, thr, freq, out);
}

extern "C" void kernel_launch(void* const* d_in, const int* in_sizes, int n_in,
                              void* d_out, int out_size, void* d_ws, size_t ws_size,
                              hipStream_t stream) {
  const float* x    = (const float*)d_in[0];
  const float* act  = (const float*)d_in[1];
  const float* thr  = (const float*)d_in[2];
  const float* freq = (const float*)d_in[3];
  const float* W    = (const float*)d_in[4];
  const void*  sp   = d_in[5];
  float* out = (float*)d_out;

  // ws: partial f32 @0 (N_CHUNKS*S*4 = 16 MB)
  const size_t need = (size_t)N_CHUNKS * S * sizeof(float);

  if (ws_size >= need) {
    float* partial = (float*)d_ws;
    dim3 g1(COL_BLOCKS, N_CHUNKS);
    lateral_selfprep<<<g1, TPB, 0, stream>>>(W, sp, partial);
    ensemble_update<<<S / TPB, TPB, 0, stream>>>(partial, x, act, thr, freq, out);
  } else {
    fused_full_int<<<S / TPB, TPB, 0, stream>>>(W, (const int*)sp, x, act, thr, freq, out);
  }
}